// Round 3
// baseline (316.323 us; speedup 1.0000x reference)
//
#include <hip/hip_runtime.h>
#include <hip/hip_bf16.h>

// B=256, N=65536, fp32 complex multiply with output layout:
//   out floats [b*2N, b*2N+N) = real[b,:], [b*2N+N, b*2N+2N) = imag[b,:]
//
// Every vector-memory instruction is lane-consecutive. Thread i of a
// 256-thread block loads input float4s (base+i) and (base+256+i) -> each
// global_load_dwordx4 covers a contiguous 1024 B span. One input float4 =
// 2 complex -> one float2 of reals + one float2 of imags, stored
// lane-consecutive via nontemporal dwordx2 stores (native clang vector type —
// HIP's float2 struct is rejected by __builtin_nontemporal_store).

typedef float vfloat2 __attribute__((ext_vector_type(2)));
typedef float vfloat4 __attribute__((ext_vector_type(4)));

__global__ __launch_bounds__(256) void cmul_kernel(
        const vfloat4* __restrict__ a,
        const vfloat4* __restrict__ b,
        vfloat2* __restrict__ out2) {
    const unsigned int base = blockIdx.x * 512u;
    const unsigned int i    = threadIdx.x;

    const unsigned int v0 = base + i;          // input float4 index, load 0
    const unsigned int v1 = base + 256u + i;   // input float4 index, load 1

    const vfloat4 a0 = a[v0];
    const vfloat4 b0 = b[v0];
    const vfloat4 a1 = a[v1];
    const vfloat4 b1 = b[v1];

    vfloat2 re0, im0, re1, im1;
    re0.x = a0.x * b0.x - a0.y * b0.y;
    im0.x = a0.y * b0.x + a0.x * b0.y;
    re0.y = a0.z * b0.z - a0.w * b0.w;
    im0.y = a0.w * b0.z + a0.z * b0.w;

    re1.x = a1.x * b1.x - a1.y * b1.y;
    im1.x = a1.y * b1.x + a1.x * b1.y;
    re1.y = a1.z * b1.z - a1.w * b1.w;
    im1.y = a1.w * b1.z + a1.z * b1.w;

    // float4 index v holds complex c=2v,2v+1 ; row b = v>>15 ;
    // in float2 units: real at row*65536 + (v & 32767), imag at +32768.
    const unsigned int r0 = (v0 >> 15) * 65536u + (v0 & 32767u);
    const unsigned int r1 = (v1 >> 15) * 65536u + (v1 & 32767u);

    __builtin_nontemporal_store(re0, &out2[r0]);
    __builtin_nontemporal_store(im0, &out2[r0 + 32768u]);
    __builtin_nontemporal_store(re1, &out2[r1]);
    __builtin_nontemporal_store(im1, &out2[r1 + 32768u]);
}

extern "C" void kernel_launch(void* const* d_in, const int* in_sizes, int n_in,
                              void* d_out, int out_size, void* d_ws, size_t ws_size,
                              hipStream_t stream) {
    const vfloat4* a = (const vfloat4*)d_in[0];
    const vfloat4* b = (const vfloat4*)d_in[1];
    vfloat2* out2 = (vfloat2*)d_out;

    // total input float4s per tensor = out_size/4 ; each block covers 512.
    const int total_f4 = out_size / 4;          // 8,388,608
    const int grid = total_f4 / 512;            // 16,384
    cmul_kernel<<<grid, 256, 0, stream>>>(a, b, out2);
}